// Round 8
// baseline (979.306 us; speedup 1.0000x reference)
//
#include <hip/hip_runtime.h>
#include <hip/hip_bf16.h>

// MultiLoRALinear: out = x@W.T + bias + (x @ A[idx]) @ B[idx]
// M=16384, K=4096, N=4096, rank 16.
//
// R8 = R7 + bottom fences on MFMA clusters.
// R7's null result (identical counters to R6: VGPR 128, WRITE 718MB, spill)
// exposed rule #18's dual: register-only MFMAs sink PAST "memory"-clobber
// asm (lgkmcnt/s_barrier), so cluster-1 MFMAs slid below the a1 ds_reads ->
// a0+b0+a1 (96 regs) live -> ~2 regs/iter scratch spill. Fix: sched_barrier(0)
// AFTER each MFMA cluster pins codegen order (compile-time only; runtime
// wave drift of the relaxed schedule preserved).

#define M_TOT 16384
#define K_TOT 4096
#define N_TOT 4096
#define RANK 16
#define NT 128   // K_TOT / 32

typedef __attribute__((ext_vector_type(8))) short bf16x8;
typedef __attribute__((ext_vector_type(4))) float f32x4;

// ---------------- fp32 -> bf16 (round-to-nearest-even) ----------------
__device__ __forceinline__ unsigned short f2bf(float f) {
  unsigned int u = __builtin_bit_cast(unsigned int, f);
  u += 0x7fffu + ((u >> 16) & 1u);
  return (unsigned short)(u >> 16);
}

__global__ void cvt_bf16_kernel(const float* __restrict__ src,
                                unsigned short* __restrict__ dst, int n4) {
  int i = blockIdx.x * blockDim.x + threadIdx.x;
  const int stride = gridDim.x * blockDim.x;
  for (; i < n4; i += stride) {
    const float4 v = reinterpret_cast<const float4*>(src)[i];
    ushort4 o;
    o.x = f2bf(v.x); o.y = f2bf(v.y); o.z = f2bf(v.z); o.w = f2bf(v.w);
    reinterpret_cast<ushort4*>(dst)[i] = o;
  }
}

// ------------- inter = x @ A[slot] via MFMA (wave: 16 rows x r16) -------------
__global__ __launch_bounds__(256) void lora_inter_mfma_kernel(
    const unsigned short* __restrict__ xb,
    const float* __restrict__ loraA,
    const int* __restrict__ idx,
    float* __restrict__ inter) {
  const int lane = threadIdx.x & 63;
  const int wv = threadIdx.x >> 6;
  const int m0 = blockIdx.x * 64 + wv * 16;
  const int slot = idx[m0 >> 11];
  const int q = lane >> 4;
  const int c = lane & 15;
  const unsigned short* __restrict__ xrow = xb + (size_t)(m0 + c) * K_TOT + q * 8;
  const float* __restrict__ Abase = loraA + (size_t)slot * K_TOT * RANK + c;

  f32x4 acc = (f32x4){0.f, 0.f, 0.f, 0.f};
#pragma unroll 4
  for (int kt = 0; kt < K_TOT; kt += 32) {
    const bf16x8 af = *reinterpret_cast<const bf16x8*>(xrow + kt);
    const float* __restrict__ Ak = Abase + (size_t)(kt + q * 8) * RANK;
    bf16x8 bfr;
#pragma unroll
    for (int j = 0; j < 8; ++j) bfr[j] = (short)f2bf(Ak[(size_t)j * RANK]);
    acc = __builtin_amdgcn_mfma_f32_16x16x32_bf16(af, bfr, acc, 0, 0, 0);
  }
#pragma unroll
  for (int i = 0; i < 4; ++i)
    inter[(size_t)(m0 + q * 4 + i) * RANK + c] = acc[i];
}

// ---------------- deep-pipelined 256x256 GEMM, 8 waves ----------------
__device__ __forceinline__ void gload16(const void* g, void* l) {
  __builtin_amdgcn_global_load_lds(
      (const __attribute__((address_space(1))) unsigned int*)g,
      (__attribute__((address_space(3))) unsigned int*)l, 16, 0, 0);
}

__global__ __launch_bounds__(512, 2) void gemm_fused_kernel(
    const unsigned short* __restrict__ xb,   // [M][K] bf16
    const unsigned short* __restrict__ wb,   // [N][K] bf16
    const float* __restrict__ bias,          // [N]
    const float* __restrict__ inter,         // [M][RANK] f32
    const float* __restrict__ loraB,         // [32][RANK][N] f32
    const int* __restrict__ idx,             // [8]
    float* __restrict__ out) {               // [M][N] f32
  // ring-4 x (A: 256x32 bf16 = 16KB, B: 16KB) = 128 KiB
  __shared__ unsigned short lds[4][16384];
  char* ldsB = (char*)lds;

  const int tid = threadIdx.x;
  const int lane = tid & 63;
  const int wv = tid >> 6;   // 0..7
  const int wr = wv >> 2;    // 0..1 (M half)
  const int wc = wv & 3;     // 0..3 (N quarter)

  // XCD-aware bijective swizzle: 1024 wgs, 8 XCDs, 128 per chunk
  const int bid = ((blockIdx.x & 7) << 7) | (blockIdx.x >> 3);
  const int m0 = (bid >> 4) << 8;   // 64 M-panels
  const int n0 = (bid & 15) << 8;   // 16 N-panels

  // ---- staging source (pre-permuted by the LDS swizzle involution) ----
  const int srow = tid >> 2;                        // 0..127
  const int sslot = (tid & 3) ^ ((srow >> 1) & 3);  // 16B slot within 64B row
  const unsigned short* xs0 = xb + (size_t)(m0 + srow) * K_TOT + sslot * 8;
  const unsigned short* xs1 = xs0 + (size_t)128 * K_TOT;
  const unsigned short* ws0 = wb + (size_t)(n0 + srow) * K_TOT + sslot * 8;
  const unsigned short* ws1 = ws0 + (size_t)128 * K_TOT;
  const int stg = wv << 10;  // wave-uniform LDS byte offset within region

#define STAGE_T(t)                                                 \
  do {                                                             \
    const int _bo = (((t) & 3) << 15);                             \
    const size_t _ko = (size_t)(t) * 32;                           \
    gload16(xs0 + _ko, ldsB + _bo + stg);                          \
    gload16(xs1 + _ko, ldsB + _bo + 8192 + stg);                   \
    gload16(ws0 + _ko, ldsB + _bo + 16384 + stg);                  \
    gload16(ws1 + _ko, ldsB + _bo + 24576 + stg);                  \
  } while (0)

  // ---- ds_read byte offsets (swizzled: phys_slot = slot ^ ((row>>1)&3)) ----
  const int rl = lane & 15;
  const int q = lane >> 4;
  const int pslot = ((q ^ ((rl >> 1) & 3)) << 4);
  const int aoff = (wr * 128 + rl) * 64 + pslot;           // + mf*1024
  const int boff = 16384 + (wc * 64 + rl) * 64 + pslot;    // + nf*1024

  f32x4 acc[8][4];
#pragma unroll
  for (int i = 0; i < 8; ++i)
#pragma unroll
    for (int j = 0; j < 4; ++j) acc[i][j] = (f32x4){0.f, 0.f, 0.f, 0.f};

  // prologue: stage tiles 0,1,2 (12 loads/thread); tile0 = 4 oldest
  STAGE_T(0); STAGE_T(1); STAGE_T(2);
  asm volatile("s_waitcnt vmcnt(8)" ::: "memory");
  __builtin_amdgcn_s_barrier();

#pragma unroll 1
  for (int t = 0; t < NT; ++t) {
    const char* Ab = ldsB + ((t & 3) << 15) + aoff;
    const char* Bb = ldsB + ((t & 3) << 15) + boff;
    if (t < NT - 3) STAGE_T(t + 3);

    // ---- sub-phase 1: a0,b0 (8 reads; <=64 fragment VGPRs live) ----
    {
      bf16x8 a0[4], b0[4];
#pragma unroll
      for (int i = 0; i < 4; ++i)
        a0[i] = *reinterpret_cast<const bf16x8*>(Ab + i * 1024);
#pragma unroll
      for (int i = 0; i < 4; ++i)
        b0[i] = *reinterpret_cast<const bf16x8*>(Bb + i * 1024);
      asm volatile("s_waitcnt lgkmcnt(0)" ::: "memory");
      __builtin_amdgcn_sched_barrier(0);
      __builtin_amdgcn_s_setprio(1);
#pragma unroll
      for (int mf = 0; mf < 4; ++mf)
#pragma unroll
        for (int nf = 0; nf < 4; ++nf)
          acc[mf][nf] = __builtin_amdgcn_mfma_f32_16x16x32_bf16(
              a0[mf], b0[nf], acc[mf][nf], 0, 0, 0);
      __builtin_amdgcn_s_setprio(0);
      // BOTTOM FENCE: keep cluster-1 MFMAs above a1's ds_reads (a0 dies here)
      __builtin_amdgcn_sched_barrier(0);

      // ---- sub-phase 2: a1 (4 reads; b0 still live -> <=64 VGPRs) ----
      bf16x8 a1[4];
#pragma unroll
      for (int i = 0; i < 4; ++i)
        a1[i] = *reinterpret_cast<const bf16x8*>(Ab + (4 + i) * 1024);
      asm volatile("s_waitcnt lgkmcnt(0)" ::: "memory");
      __builtin_amdgcn_sched_barrier(0);
      __builtin_amdgcn_s_setprio(1);
#pragma unroll
      for (int mf = 0; mf < 4; ++mf)
#pragma unroll
        for (int nf = 0; nf < 4; ++nf)
          acc[4 + mf][nf] = __builtin_amdgcn_mfma_f32_16x16x32_bf16(
              a1[mf], b0[nf], acc[4 + mf][nf], 0, 0, 0);
      __builtin_amdgcn_s_setprio(0);
      // BOTTOM FENCE: keep cluster-2 MFMAs (and a1/b0 lifetimes) inside tile t
      __builtin_amdgcn_sched_barrier(0);
    }

    // tile boundary: guarantee tile t+1 resident before next iteration
    if (t < NT - 3) {
      asm volatile("s_waitcnt vmcnt(8)" ::: "memory");
    } else if (t == NT - 3) {
      asm volatile("s_waitcnt vmcnt(4)" ::: "memory");
    } else {
      asm volatile("s_waitcnt vmcnt(0)" ::: "memory");
    }
    __builtin_amdgcn_s_barrier();
  }

  // ---------------- epilogue: + bias + inter @ B[slot] ----------------
  const int slot = idx[m0 >> 11];
  const float* __restrict__ Bmat = loraB + (size_t)slot * RANK * N_TOT;
  const int gn0 = n0 + wc * 64 + rl;

#pragma unroll
  for (int nf = 0; nf < 4; ++nf) {
    const int gn = gn0 + nf * 16;
    const float bv = bias[gn];
    float bcv[RANK];
#pragma unroll
    for (int p = 0; p < RANK; ++p) bcv[p] = Bmat[(size_t)p * N_TOT + gn];
#pragma unroll
    for (int mf = 0; mf < 8; ++mf) {
      const int gmb = m0 + wr * 128 + mf * 16 + (q << 2);
#pragma unroll
      for (int r = 0; r < 4; ++r) {
        const int gm = gmb + r;
        const float4* ivp = reinterpret_cast<const float4*>(inter + (size_t)gm * RANK);
        const float4 iv0 = ivp[0], iv1 = ivp[1], iv2 = ivp[2], iv3 = ivp[3];
        const float lora =
            iv0.x * bcv[0]  + iv0.y * bcv[1]  + iv0.z * bcv[2]  + iv0.w * bcv[3] +
            iv1.x * bcv[4]  + iv1.y * bcv[5]  + iv1.z * bcv[6]  + iv1.w * bcv[7] +
            iv2.x * bcv[8]  + iv2.y * bcv[9]  + iv2.z * bcv[10] + iv2.w * bcv[11] +
            iv3.x * bcv[12] + iv3.y * bcv[13] + iv3.z * bcv[14] + iv3.w * bcv[15];
        out[(size_t)gm * N_TOT + gn] = acc[mf][nf][r] + bv + lora;
      }
    }
  }
#undef STAGE_T
}

// ---------------- host launcher ----------------
extern "C" void kernel_launch(void* const* d_in, const int* in_sizes, int n_in,
                              void* d_out, int out_size, void* d_ws, size_t ws_size,
                              hipStream_t stream) {
  const float* x     = (const float*)d_in[0];  // [8,2048,4096]
  const float* w     = (const float*)d_in[1];  // [4096,4096]
  const float* bias  = (const float*)d_in[2];  // [4096]
  const float* loraA = (const float*)d_in[3];  // [32,4096,16]
  const float* loraB = (const float*)d_in[4];  // [32,16,4096]
  const int*   idx   = (const int*)d_in[5];    // [8]
  float* out = (float*)d_out;

  char* ws = (char*)d_ws;
  unsigned short* xb   = (unsigned short*)ws;                  // 134,217,728 B
  unsigned short* wbuf = (unsigned short*)(ws + 134217728);    //  33,554,432 B
  float* inter = (float*)(ws + 134217728 + 33554432);          //   1,048,576 B

  cvt_bf16_kernel<<<2048, 256, 0, stream>>>(x, xb, M_TOT * K_TOT / 4);
  cvt_bf16_kernel<<<1024, 256, 0, stream>>>(w, wbuf, N_TOT * K_TOT / 4);
  lora_inter_mfma_kernel<<<M_TOT / 64, 256, 0, stream>>>(xb, loraA, idx, inter);
  gemm_fused_kernel<<<(M_TOT / 256) * (N_TOT / 256), 512, 0, stream>>>(
      xb, wbuf, bias, inter, loraB, idx, out);
}

// Round 9
// 958.771 us; speedup vs baseline: 1.0214x; 1.0214x over previous
//
#include <hip/hip_runtime.h>
#include <hip/hip_bf16.h>

// MultiLoRALinear: out = x@W.T + bias + (x @ A[idx]) @ B[idx]
// M=16384, K=4096, N=4096, rank 16.
//
// R9 = known-best composite: R4's GEMM (605us, VGPR 120, no spill) +
// R5's pre-pass (cvt x / cvt w / MFMA inter, ~90us).
// R6/R7/R8 lesson (3 nulls at 857us): at 512 threads the HW cap is 256
// regs/thread (2 waves/SIMD x 512-reg file). acc(128 AGPR) + 96 live
// fragments + ~30 addr > 256 -> 2-reg/iter scratch spill. Only structural
// barriers (this kernel) or dataflow deps bind the allocator; lgkmcnt asm /
// sched_barrier / setprio hints all failed to.

#define M_TOT 16384
#define K_TOT 4096
#define N_TOT 4096
#define RANK 16
#define NT 128   // K_TOT / 32

typedef __attribute__((ext_vector_type(8))) short bf16x8;
typedef __attribute__((ext_vector_type(4))) float f32x4;

// ---------------- fp32 -> bf16 (round-to-nearest-even) ----------------
__device__ __forceinline__ unsigned short f2bf(float f) {
  unsigned int u = __builtin_bit_cast(unsigned int, f);
  u += 0x7fffu + ((u >> 16) & 1u);
  return (unsigned short)(u >> 16);
}

__global__ void cvt_bf16_kernel(const float* __restrict__ src,
                                unsigned short* __restrict__ dst, int n4) {
  int i = blockIdx.x * blockDim.x + threadIdx.x;
  const int stride = gridDim.x * blockDim.x;
  for (; i < n4; i += stride) {
    const float4 v = reinterpret_cast<const float4*>(src)[i];
    ushort4 o;
    o.x = f2bf(v.x); o.y = f2bf(v.y); o.z = f2bf(v.z); o.w = f2bf(v.w);
    reinterpret_cast<ushort4*>(dst)[i] = o;
  }
}

// ------------- inter = x @ A[slot] via MFMA (wave: 16 rows x r16) -------------
__global__ __launch_bounds__(256) void lora_inter_mfma_kernel(
    const unsigned short* __restrict__ xb,
    const float* __restrict__ loraA,
    const int* __restrict__ idx,
    float* __restrict__ inter) {
  const int lane = threadIdx.x & 63;
  const int wv = threadIdx.x >> 6;
  const int m0 = blockIdx.x * 64 + wv * 16;
  const int slot = idx[m0 >> 11];
  const int q = lane >> 4;
  const int c = lane & 15;
  const unsigned short* __restrict__ xrow = xb + (size_t)(m0 + c) * K_TOT + q * 8;
  const float* __restrict__ Abase = loraA + (size_t)slot * K_TOT * RANK + c;

  f32x4 acc = (f32x4){0.f, 0.f, 0.f, 0.f};
#pragma unroll 4
  for (int kt = 0; kt < K_TOT; kt += 32) {
    const bf16x8 af = *reinterpret_cast<const bf16x8*>(xrow + kt);
    const float* __restrict__ Ak = Abase + (size_t)(kt + q * 8) * RANK;
    bf16x8 bfr;
#pragma unroll
    for (int j = 0; j < 8; ++j) bfr[j] = (short)f2bf(Ak[(size_t)j * RANK]);
    acc = __builtin_amdgcn_mfma_f32_16x16x32_bf16(af, bfr, acc, 0, 0, 0);
  }
#pragma unroll
  for (int i = 0; i < 4; ++i)
    inter[(size_t)(m0 + q * 4 + i) * RANK + c] = acc[i];
}

// ---------------- deep-pipelined 256x256 GEMM (R4 structure) ----------------
__device__ __forceinline__ void gload16(const void* g, void* l) {
  __builtin_amdgcn_global_load_lds(
      (const __attribute__((address_space(1))) unsigned int*)g,
      (__attribute__((address_space(3))) unsigned int*)l, 16, 0, 0);
}

#define GBARRIER() asm volatile("s_barrier" ::: "memory")
#define WAIT_LGKM0()                                   \
  do {                                                 \
    asm volatile("s_waitcnt lgkmcnt(0)" ::: "memory"); \
    __builtin_amdgcn_sched_barrier(0);                 \
  } while (0)

__global__ __launch_bounds__(512, 2) void gemm_fused_kernel(
    const unsigned short* __restrict__ xb,   // [M][K] bf16
    const unsigned short* __restrict__ wb,   // [N][K] bf16
    const float* __restrict__ bias,          // [N]
    const float* __restrict__ inter,         // [M][RANK] f32
    const float* __restrict__ loraB,         // [32][RANK][N] f32
    const int* __restrict__ idx,             // [8]
    float* __restrict__ out) {               // [M][N] f32
  // 4 ring buffers x (A: 256x32 bf16 = 16KB, B: 16KB) = 128 KiB
  __shared__ unsigned short lds[4][16384];
  char* ldsB = (char*)&lds[0][0];

  const int tid = threadIdx.x;
  const int lane = tid & 63;
  const int wv = tid >> 6;   // 0..7
  const int wr = wv >> 2;    // 0..1 (M half)
  const int wc = wv & 3;     // 0..3 (N quarter)

  // XCD-aware bijective swizzle: 1024 wgs, 8 XCDs, 128 per chunk
  const int bid = ((blockIdx.x & 7) << 7) | (blockIdx.x >> 3);
  const int m0 = (bid >> 4) << 8;   // 64 M-panels
  const int n0 = (bid & 15) << 8;   // 16 N-panels

  // ---- staging source (pre-permuted by the LDS swizzle involution) ----
  const int srow = tid >> 2;                        // 0..127
  const int sslot = (tid & 3) ^ ((srow >> 1) & 3);  // 16B slot within 64B row
  const unsigned short* xs0 = xb + (size_t)(m0 + srow) * K_TOT + sslot * 8;
  const unsigned short* xs1 = xs0 + (size_t)128 * K_TOT;
  const unsigned short* ws0 = wb + (size_t)(n0 + srow) * K_TOT + sslot * 8;
  const unsigned short* ws1 = ws0 + (size_t)128 * K_TOT;
  const int stgoff = wv << 10;  // wave-uniform LDS byte offset within region

#define STAGE_A(t)                                                  \
  do {                                                              \
    const int _bo = (((t) & 3) << 15);                              \
    gload16(xs0 + (size_t)(t) * 32, ldsB + _bo + stgoff);           \
    gload16(xs1 + (size_t)(t) * 32, ldsB + _bo + 8192 + stgoff);    \
  } while (0)
#define STAGE_B(t)                                                  \
  do {                                                              \
    const int _bo = (((t) & 3) << 15);                              \
    gload16(ws0 + (size_t)(t) * 32, ldsB + _bo + 16384 + stgoff);   \
    gload16(ws1 + (size_t)(t) * 32, ldsB + _bo + 24576 + stgoff);   \
  } while (0)

  // ---- ds_read byte offsets (swizzled: phys_slot = slot ^ ((row>>1)&3)) ----
  const int rl = lane & 15;
  const int q = lane >> 4;
  const int pslot = ((q ^ ((rl >> 1) & 3)) << 4);
  const int aoff = (wr * 128 + rl) * 64 + pslot;           // + mf*1024
  const int boff = 16384 + (wc * 64 + rl) * 64 + pslot;    // + nf*1024

  f32x4 acc[8][4];
#pragma unroll
  for (int i = 0; i < 8; ++i)
#pragma unroll
    for (int j = 0; j < 4; ++j) acc[i][j] = (f32x4){0.f, 0.f, 0.f, 0.f};

  // ---- prologue: stage tiles 0,1,2; wait for tile 0 (4 oldest of 12) ----
  STAGE_A(0); STAGE_B(0);
  STAGE_A(1); STAGE_B(1);
  STAGE_A(2); STAGE_B(2);
  asm volatile("s_waitcnt vmcnt(8)" ::: "memory");
  GBARRIER();

#pragma unroll 1
  for (int t = 0; t < NT; ++t) {
    const char* Ab = ldsB + ((t & 3) << 15) + aoff;
    const char* Bb = ldsB + ((t & 3) << 15) + boff;
    bf16x8 afrag[4], bfrag[4];

    // ---------------- phase 1: acc[0..3][0..3] ----------------
#pragma unroll
    for (int nf = 0; nf < 4; ++nf)
      bfrag[nf] = *reinterpret_cast<const bf16x8*>(Bb + nf * 1024);
#pragma unroll
    for (int mf = 0; mf < 4; ++mf)
      afrag[mf] = *reinterpret_cast<const bf16x8*>(Ab + mf * 1024);
    if (t < NT - 3) STAGE_A(t + 3);
    GBARRIER();
    WAIT_LGKM0();
    __builtin_amdgcn_s_setprio(1);
#pragma unroll
    for (int mf = 0; mf < 4; ++mf)
#pragma unroll
      for (int nf = 0; nf < 4; ++nf)
        acc[mf][nf] = __builtin_amdgcn_mfma_f32_16x16x32_bf16(
            afrag[mf], bfrag[nf], acc[mf][nf], 0, 0, 0);
    __builtin_amdgcn_s_setprio(0);
    GBARRIER();

    // ---------------- phase 2: acc[4..7][0..3] ----------------
#pragma unroll
    for (int mf = 0; mf < 4; ++mf)
      afrag[mf] = *reinterpret_cast<const bf16x8*>(Ab + (4 + mf) * 1024);
    if (t < NT - 3) STAGE_B(t + 3);
    GBARRIER();
    WAIT_LGKM0();
    __builtin_amdgcn_s_setprio(1);
#pragma unroll
    for (int mf = 0; mf < 4; ++mf)
#pragma unroll
      for (int nf = 0; nf < 4; ++nf)
        acc[4 + mf][nf] = __builtin_amdgcn_mfma_f32_16x16x32_bf16(
            afrag[mf], bfrag[nf], acc[4 + mf][nf], 0, 0, 0);
    __builtin_amdgcn_s_setprio(0);
    // tile boundary: guarantee tile t+1 resident (4 oldest of <=12 in flight)
    if (t < NT - 3) {
      asm volatile("s_waitcnt vmcnt(8)" ::: "memory");
    } else {
      asm volatile("s_waitcnt vmcnt(0)" ::: "memory");
    }
    GBARRIER();
  }

  // ---------------- epilogue: + bias + inter @ B[slot] ----------------
  const int slot = idx[m0 >> 11];
  const float* __restrict__ Bmat = loraB + (size_t)slot * RANK * N_TOT;
  const int gn0 = n0 + wc * 64 + rl;

#pragma unroll
  for (int nf = 0; nf < 4; ++nf) {
    const int gn = gn0 + nf * 16;
    const float bv = bias[gn];
    float bcv[RANK];
#pragma unroll
    for (int p = 0; p < RANK; ++p) bcv[p] = Bmat[(size_t)p * N_TOT + gn];
#pragma unroll
    for (int mf = 0; mf < 8; ++mf) {
      const int gmb = m0 + wr * 128 + mf * 16 + (q << 2);
#pragma unroll
      for (int r = 0; r < 4; ++r) {
        const int gm = gmb + r;
        const float4* ivp = reinterpret_cast<const float4*>(inter + (size_t)gm * RANK);
        const float4 iv0 = ivp[0], iv1 = ivp[1], iv2 = ivp[2], iv3 = ivp[3];
        const float lora =
            iv0.x * bcv[0]  + iv0.y * bcv[1]  + iv0.z * bcv[2]  + iv0.w * bcv[3] +
            iv1.x * bcv[4]  + iv1.y * bcv[5]  + iv1.z * bcv[6]  + iv1.w * bcv[7] +
            iv2.x * bcv[8]  + iv2.y * bcv[9]  + iv2.z * bcv[10] + iv2.w * bcv[11] +
            iv3.x * bcv[12] + iv3.y * bcv[13] + iv3.z * bcv[14] + iv3.w * bcv[15];
        out[(size_t)gm * N_TOT + gn] = acc[mf][nf][r] + bv + lora;
      }
    }
  }
#undef STAGE_A
#undef STAGE_B
}

// ---------------- host launcher ----------------
extern "C" void kernel_launch(void* const* d_in, const int* in_sizes, int n_in,
                              void* d_out, int out_size, void* d_ws, size_t ws_size,
                              hipStream_t stream) {
  const float* x     = (const float*)d_in[0];  // [8,2048,4096]
  const float* w     = (const float*)d_in[1];  // [4096,4096]
  const float* bias  = (const float*)d_in[2];  // [4096]
  const float* loraA = (const float*)d_in[3];  // [32,4096,16]
  const float* loraB = (const float*)d_in[4];  // [32,16,4096]
  const int*   idx   = (const int*)d_in[5];    // [8]
  float* out = (float*)d_out;

  char* ws = (char*)d_ws;
  unsigned short* xb   = (unsigned short*)ws;                  // 134,217,728 B
  unsigned short* wbuf = (unsigned short*)(ws + 134217728);    //  33,554,432 B
  float* inter = (float*)(ws + 134217728 + 33554432);          //   1,048,576 B

  cvt_bf16_kernel<<<2048, 256, 0, stream>>>(x, xb, M_TOT * K_TOT / 4);
  cvt_bf16_kernel<<<1024, 256, 0, stream>>>(w, wbuf, N_TOT * K_TOT / 4);
  lora_inter_mfma_kernel<<<M_TOT / 64, 256, 0, stream>>>(xb, loraA, idx, inter);
  gemm_fused_kernel<<<(M_TOT / 256) * (N_TOT / 256), 512, 0, stream>>>(
      xb, wbuf, bias, inter, loraB, idx, out);
}

// Round 10
// 692.382 us; speedup vs baseline: 1.4144x; 1.3847x over previous
//
#include <hip/hip_runtime.h>
#include <hip/hip_bf16.h>

// MultiLoRALinear: out = x@W.T + bias + (x @ A[idx]) @ B[idx]
// M=16384, K=4096, N=4096, rank 16.
//
// R10 = R9 with R4's EPILOGUE restored (single-variable fix).
// R9 falsified the R6-R8 "K-loop fragment liveness" theory by control: R9's
// K-loop was byte-identical to R4 yet spilled (VGPR 128, WRITE 695MB,
// 877us). The only diff was the epilogue I rewrote in R6: nf-outer with
// inter reloaded per nf -> allocator hoists nf-invariant inter loads ->
// liveness > cap -> ~430MB scratch. R4's epilogue (restored here): hoist
// bcv[4][16]+bv[4], load inter ONCE per (mf,r), 4 row-local stores.

#define M_TOT 16384
#define K_TOT 4096
#define N_TOT 4096
#define RANK 16
#define NT 128   // K_TOT / 32

typedef __attribute__((ext_vector_type(8))) short bf16x8;
typedef __attribute__((ext_vector_type(4))) float f32x4;

// ---------------- fp32 -> bf16 (round-to-nearest-even) ----------------
__device__ __forceinline__ unsigned short f2bf(float f) {
  unsigned int u = __builtin_bit_cast(unsigned int, f);
  u += 0x7fffu + ((u >> 16) & 1u);
  return (unsigned short)(u >> 16);
}

__global__ void cvt_bf16_kernel(const float* __restrict__ src,
                                unsigned short* __restrict__ dst, int n4) {
  int i = blockIdx.x * blockDim.x + threadIdx.x;
  const int stride = gridDim.x * blockDim.x;
  for (; i < n4; i += stride) {
    const float4 v = reinterpret_cast<const float4*>(src)[i];
    ushort4 o;
    o.x = f2bf(v.x); o.y = f2bf(v.y); o.z = f2bf(v.z); o.w = f2bf(v.w);
    reinterpret_cast<ushort4*>(dst)[i] = o;
  }
}

// ------------- inter = x @ A[slot] via MFMA (wave: 16 rows x r16) -------------
__global__ __launch_bounds__(256) void lora_inter_mfma_kernel(
    const unsigned short* __restrict__ xb,
    const float* __restrict__ loraA,
    const int* __restrict__ idx,
    float* __restrict__ inter) {
  const int lane = threadIdx.x & 63;
  const int wv = threadIdx.x >> 6;
  const int m0 = blockIdx.x * 64 + wv * 16;
  const int slot = idx[m0 >> 11];
  const int q = lane >> 4;
  const int c = lane & 15;
  const unsigned short* __restrict__ xrow = xb + (size_t)(m0 + c) * K_TOT + q * 8;
  const float* __restrict__ Abase = loraA + (size_t)slot * K_TOT * RANK + c;

  f32x4 acc = (f32x4){0.f, 0.f, 0.f, 0.f};
#pragma unroll 4
  for (int kt = 0; kt < K_TOT; kt += 32) {
    const bf16x8 af = *reinterpret_cast<const bf16x8*>(xrow + kt);
    const float* __restrict__ Ak = Abase + (size_t)(kt + q * 8) * RANK;
    bf16x8 bfr;
#pragma unroll
    for (int j = 0; j < 8; ++j) bfr[j] = (short)f2bf(Ak[(size_t)j * RANK]);
    acc = __builtin_amdgcn_mfma_f32_16x16x32_bf16(af, bfr, acc, 0, 0, 0);
  }
#pragma unroll
  for (int i = 0; i < 4; ++i)
    inter[(size_t)(m0 + q * 4 + i) * RANK + c] = acc[i];
}

// ---------------- deep-pipelined 256x256 GEMM (R4 structure) ----------------
__device__ __forceinline__ void gload16(const void* g, void* l) {
  __builtin_amdgcn_global_load_lds(
      (const __attribute__((address_space(1))) unsigned int*)g,
      (__attribute__((address_space(3))) unsigned int*)l, 16, 0, 0);
}

#define GBARRIER() asm volatile("s_barrier" ::: "memory")
#define WAIT_LGKM0()                                   \
  do {                                                 \
    asm volatile("s_waitcnt lgkmcnt(0)" ::: "memory"); \
    __builtin_amdgcn_sched_barrier(0);                 \
  } while (0)

__global__ __launch_bounds__(512, 2) void gemm_fused_kernel(
    const unsigned short* __restrict__ xb,   // [M][K] bf16
    const unsigned short* __restrict__ wb,   // [N][K] bf16
    const float* __restrict__ bias,          // [N]
    const float* __restrict__ inter,         // [M][RANK] f32
    const float* __restrict__ loraB,         // [32][RANK][N] f32
    const int* __restrict__ idx,             // [8]
    float* __restrict__ out) {               // [M][N] f32
  // 4 ring buffers x (A: 256x32 bf16 = 16KB, B: 16KB) = 128 KiB
  __shared__ unsigned short lds[4][16384];
  char* ldsB = (char*)&lds[0][0];

  const int tid = threadIdx.x;
  const int lane = tid & 63;
  const int wv = tid >> 6;   // 0..7
  const int wr = wv >> 2;    // 0..1 (M half)
  const int wc = wv & 3;     // 0..3 (N quarter)

  // XCD-aware bijective swizzle: 1024 wgs, 8 XCDs, 128 per chunk
  const int bid = ((blockIdx.x & 7) << 7) | (blockIdx.x >> 3);
  const int m0 = (bid >> 4) << 8;   // 64 M-panels
  const int n0 = (bid & 15) << 8;   // 16 N-panels

  // ---- staging source (pre-permuted by the LDS swizzle involution) ----
  const int srow = tid >> 2;                        // 0..127
  const int sslot = (tid & 3) ^ ((srow >> 1) & 3);  // 16B slot within 64B row
  const unsigned short* xs0 = xb + (size_t)(m0 + srow) * K_TOT + sslot * 8;
  const unsigned short* xs1 = xs0 + (size_t)128 * K_TOT;
  const unsigned short* ws0 = wb + (size_t)(n0 + srow) * K_TOT + sslot * 8;
  const unsigned short* ws1 = ws0 + (size_t)128 * K_TOT;
  const int stgoff = wv << 10;  // wave-uniform LDS byte offset within region

#define STAGE_A(t)                                                  \
  do {                                                              \
    const int _bo = (((t) & 3) << 15);                              \
    gload16(xs0 + (size_t)(t) * 32, ldsB + _bo + stgoff);           \
    gload16(xs1 + (size_t)(t) * 32, ldsB + _bo + 8192 + stgoff);    \
  } while (0)
#define STAGE_B(t)                                                  \
  do {                                                              \
    const int _bo = (((t) & 3) << 15);                              \
    gload16(ws0 + (size_t)(t) * 32, ldsB + _bo + 16384 + stgoff);   \
    gload16(ws1 + (size_t)(t) * 32, ldsB + _bo + 24576 + stgoff);   \
  } while (0)

  // ---- ds_read byte offsets (swizzled: phys_slot = slot ^ ((row>>1)&3)) ----
  const int rl = lane & 15;
  const int q = lane >> 4;
  const int pslot = ((q ^ ((rl >> 1) & 3)) << 4);
  const int aoff = (wr * 128 + rl) * 64 + pslot;           // + mf*1024
  const int boff = 16384 + (wc * 64 + rl) * 64 + pslot;    // + nf*1024

  f32x4 acc[8][4];
#pragma unroll
  for (int i = 0; i < 8; ++i)
#pragma unroll
    for (int j = 0; j < 4; ++j) acc[i][j] = (f32x4){0.f, 0.f, 0.f, 0.f};

  // ---- prologue: stage tiles 0,1,2; wait for tile 0 (4 oldest of 12) ----
  STAGE_A(0); STAGE_B(0);
  STAGE_A(1); STAGE_B(1);
  STAGE_A(2); STAGE_B(2);
  asm volatile("s_waitcnt vmcnt(8)" ::: "memory");
  GBARRIER();

#pragma unroll 1
  for (int t = 0; t < NT; ++t) {
    const char* Ab = ldsB + ((t & 3) << 15) + aoff;
    const char* Bb = ldsB + ((t & 3) << 15) + boff;
    bf16x8 afrag[4], bfrag[4];

    // ---------------- phase 1: acc[0..3][0..3] ----------------
#pragma unroll
    for (int nf = 0; nf < 4; ++nf)
      bfrag[nf] = *reinterpret_cast<const bf16x8*>(Bb + nf * 1024);
#pragma unroll
    for (int mf = 0; mf < 4; ++mf)
      afrag[mf] = *reinterpret_cast<const bf16x8*>(Ab + mf * 1024);
    if (t < NT - 3) STAGE_A(t + 3);
    GBARRIER();
    WAIT_LGKM0();
    __builtin_amdgcn_s_setprio(1);
#pragma unroll
    for (int mf = 0; mf < 4; ++mf)
#pragma unroll
      for (int nf = 0; nf < 4; ++nf)
        acc[mf][nf] = __builtin_amdgcn_mfma_f32_16x16x32_bf16(
            afrag[mf], bfrag[nf], acc[mf][nf], 0, 0, 0);
    __builtin_amdgcn_s_setprio(0);
    GBARRIER();

    // ---------------- phase 2: acc[4..7][0..3] ----------------
#pragma unroll
    for (int mf = 0; mf < 4; ++mf)
      afrag[mf] = *reinterpret_cast<const bf16x8*>(Ab + (4 + mf) * 1024);
    if (t < NT - 3) STAGE_B(t + 3);
    GBARRIER();
    WAIT_LGKM0();
    __builtin_amdgcn_s_setprio(1);
#pragma unroll
    for (int mf = 0; mf < 4; ++mf)
#pragma unroll
      for (int nf = 0; nf < 4; ++nf)
        acc[4 + mf][nf] = __builtin_amdgcn_mfma_f32_16x16x32_bf16(
            afrag[mf], bfrag[nf], acc[4 + mf][nf], 0, 0, 0);
    __builtin_amdgcn_s_setprio(0);
    // tile boundary: guarantee tile t+1 resident (4 oldest of <=12 in flight)
    if (t < NT - 3) {
      asm volatile("s_waitcnt vmcnt(8)" ::: "memory");
    } else {
      asm volatile("s_waitcnt vmcnt(0)" ::: "memory");
    }
    GBARRIER();
  }

  // ------------- epilogue (R4 structure): + bias + inter @ B[slot] -------------
  const int slot = idx[m0 >> 11];  // block spans one batch (256 | 2048)
  const float* __restrict__ Bmat = loraB + (size_t)slot * RANK * N_TOT;
  const int gn0 = n0 + wc * 64 + rl;

  float bcv[4][RANK];
  float bv[4];
#pragma unroll
  for (int nf = 0; nf < 4; ++nf) {
    const int gn = gn0 + nf * 16;
    bv[nf] = bias[gn];
#pragma unroll
    for (int p = 0; p < RANK; ++p) bcv[nf][p] = Bmat[(size_t)p * N_TOT + gn];
  }
#pragma unroll
  for (int mf = 0; mf < 8; ++mf) {
    const int gmb = m0 + wr * 128 + mf * 16 + (q << 2);
#pragma unroll
    for (int r = 0; r < 4; ++r) {
      const int gm = gmb + r;
      const float4* ivp = reinterpret_cast<const float4*>(inter + (size_t)gm * RANK);
      const float4 iv0 = ivp[0], iv1 = ivp[1], iv2 = ivp[2], iv3 = ivp[3];
      float* orow = out + (size_t)gm * N_TOT;
#pragma unroll
      for (int nf = 0; nf < 4; ++nf) {
        const float lora =
            iv0.x * bcv[nf][0]  + iv0.y * bcv[nf][1]  + iv0.z * bcv[nf][2]  + iv0.w * bcv[nf][3] +
            iv1.x * bcv[nf][4]  + iv1.y * bcv[nf][5]  + iv1.z * bcv[nf][6]  + iv1.w * bcv[nf][7] +
            iv2.x * bcv[nf][8]  + iv2.y * bcv[nf][9]  + iv2.z * bcv[nf][10] + iv2.w * bcv[nf][11] +
            iv3.x * bcv[nf][12] + iv3.y * bcv[nf][13] + iv3.z * bcv[nf][14] + iv3.w * bcv[nf][15];
        orow[gn0 + nf * 16] = acc[mf][nf][r] + bv[nf] + lora;
      }
    }
  }
#undef STAGE_A
#undef STAGE_B
}

// ---------------- host launcher ----------------
extern "C" void kernel_launch(void* const* d_in, const int* in_sizes, int n_in,
                              void* d_out, int out_size, void* d_ws, size_t ws_size,
                              hipStream_t stream) {
  const float* x     = (const float*)d_in[0];  // [8,2048,4096]
  const float* w     = (const float*)d_in[1];  // [4096,4096]
  const float* bias  = (const float*)d_in[2];  // [4096]
  const float* loraA = (const float*)d_in[3];  // [32,4096,16]
  const float* loraB = (const float*)d_in[4];  // [32,16,4096]
  const int*   idx   = (const int*)d_in[5];    // [8]
  float* out = (float*)d_out;

  char* ws = (char*)d_ws;
  unsigned short* xb   = (unsigned short*)ws;                  // 134,217,728 B
  unsigned short* wbuf = (unsigned short*)(ws + 134217728);    //  33,554,432 B
  float* inter = (float*)(ws + 134217728 + 33554432);          //   1,048,576 B

  cvt_bf16_kernel<<<2048, 256, 0, stream>>>(x, xb, M_TOT * K_TOT / 4);
  cvt_bf16_kernel<<<1024, 256, 0, stream>>>(w, wbuf, N_TOT * K_TOT / 4);
  lora_inter_mfma_kernel<<<M_TOT / 64, 256, 0, stream>>>(xb, loraA, idx, inter);
  gemm_fused_kernel<<<(M_TOT / 256) * (N_TOT / 256), 512, 0, stream>>>(
      xb, wbuf, bias, inter, loraB, idx, out);
}

// Round 11
// 671.752 us; speedup vs baseline: 1.4578x; 1.0307x over previous
//
#include <hip/hip_runtime.h>
#include <hip/hip_bf16.h>

// MultiLoRALinear: out = x@W.T + bias + (x @ A[idx]) @ B[idx]
// M=16384, K=4096, N=4096, rank 16.
//
// R11 = R10 with the K-loop's 4 barriers/tile collapsed to 1.
// Model: per-tile 2845 cyc = 750 LDS + 310 MFMA + ~1700 barrier skew (4
// barriers x 8-wave lockstep over 155-500cyc phases). Ring-4 + counted
// vmcnt needs only the END-of-tile barrier: stage(t+3) writes buf[(t-1)&3]
// (no reader after that barrier), vmcnt(8) before it covers tile t+1's
// residency for all waves. Liveness: 12 frags (96 VGPR) + ~25 addr <= 128
// arch + acc 128 AGPR = 249 <= 256 cap. R6-R8's "relaxed schedule spills"
// was falsified by R9/R10 (epilogue was the culprit) - this is the first
// clean test. Epilogue/pre-pass verbatim R10.

#define M_TOT 16384
#define K_TOT 4096
#define N_TOT 4096
#define RANK 16
#define NT 128   // K_TOT / 32

typedef __attribute__((ext_vector_type(8))) short bf16x8;
typedef __attribute__((ext_vector_type(4))) float f32x4;

// ---------------- fp32 -> bf16 (round-to-nearest-even) ----------------
__device__ __forceinline__ unsigned short f2bf(float f) {
  unsigned int u = __builtin_bit_cast(unsigned int, f);
  u += 0x7fffu + ((u >> 16) & 1u);
  return (unsigned short)(u >> 16);
}

__global__ void cvt_bf16_kernel(const float* __restrict__ src,
                                unsigned short* __restrict__ dst, int n4) {
  int i = blockIdx.x * blockDim.x + threadIdx.x;
  const int stride = gridDim.x * blockDim.x;
  for (; i < n4; i += stride) {
    const float4 v = reinterpret_cast<const float4*>(src)[i];
    ushort4 o;
    o.x = f2bf(v.x); o.y = f2bf(v.y); o.z = f2bf(v.z); o.w = f2bf(v.w);
    reinterpret_cast<ushort4*>(dst)[i] = o;
  }
}

// ------------- inter = x @ A[slot] via MFMA (wave: 16 rows x r16) -------------
__global__ __launch_bounds__(256) void lora_inter_mfma_kernel(
    const unsigned short* __restrict__ xb,
    const float* __restrict__ loraA,
    const int* __restrict__ idx,
    float* __restrict__ inter) {
  const int lane = threadIdx.x & 63;
  const int wv = threadIdx.x >> 6;
  const int m0 = blockIdx.x * 64 + wv * 16;
  const int slot = idx[m0 >> 11];
  const int q = lane >> 4;
  const int c = lane & 15;
  const unsigned short* __restrict__ xrow = xb + (size_t)(m0 + c) * K_TOT + q * 8;
  const float* __restrict__ Abase = loraA + (size_t)slot * K_TOT * RANK + c;

  f32x4 acc = (f32x4){0.f, 0.f, 0.f, 0.f};
#pragma unroll 4
  for (int kt = 0; kt < K_TOT; kt += 32) {
    const bf16x8 af = *reinterpret_cast<const bf16x8*>(xrow + kt);
    const float* __restrict__ Ak = Abase + (size_t)(kt + q * 8) * RANK;
    bf16x8 bfr;
#pragma unroll
    for (int j = 0; j < 8; ++j) bfr[j] = (short)f2bf(Ak[(size_t)j * RANK]);
    acc = __builtin_amdgcn_mfma_f32_16x16x32_bf16(af, bfr, acc, 0, 0, 0);
  }
#pragma unroll
  for (int i = 0; i < 4; ++i)
    inter[(size_t)(m0 + q * 4 + i) * RANK + c] = acc[i];
}

// ---------------- deep-pipelined 256x256 GEMM ----------------
__device__ __forceinline__ void gload16(const void* g, void* l) {
  __builtin_amdgcn_global_load_lds(
      (const __attribute__((address_space(1))) unsigned int*)g,
      (__attribute__((address_space(3))) unsigned int*)l, 16, 0, 0);
}

#define GBARRIER() asm volatile("s_barrier" ::: "memory")

__global__ __launch_bounds__(512, 2) void gemm_fused_kernel(
    const unsigned short* __restrict__ xb,   // [M][K] bf16
    const unsigned short* __restrict__ wb,   // [N][K] bf16
    const float* __restrict__ bias,          // [N]
    const float* __restrict__ inter,         // [M][RANK] f32
    const float* __restrict__ loraB,         // [32][RANK][N] f32
    const int* __restrict__ idx,             // [8]
    float* __restrict__ out) {               // [M][N] f32
  // 4 ring buffers x (A: 256x32 bf16 = 16KB, B: 16KB) = 128 KiB
  __shared__ unsigned short lds[4][16384];
  char* ldsB = (char*)&lds[0][0];

  const int tid = threadIdx.x;
  const int lane = tid & 63;
  const int wv = tid >> 6;   // 0..7
  const int wr = wv >> 2;    // 0..1 (M half)
  const int wc = wv & 3;     // 0..3 (N quarter)

  // XCD-aware bijective swizzle: 1024 wgs, 8 XCDs, 128 per chunk
  const int bid = ((blockIdx.x & 7) << 7) | (blockIdx.x >> 3);
  const int m0 = (bid >> 4) << 8;   // 64 M-panels
  const int n0 = (bid & 15) << 8;   // 16 N-panels

  // ---- staging source (pre-permuted by the LDS swizzle involution) ----
  const int srow = tid >> 2;                        // 0..127
  const int sslot = (tid & 3) ^ ((srow >> 1) & 3);  // 16B slot within 64B row
  const unsigned short* xs0 = xb + (size_t)(m0 + srow) * K_TOT + sslot * 8;
  const unsigned short* xs1 = xs0 + (size_t)128 * K_TOT;
  const unsigned short* ws0 = wb + (size_t)(n0 + srow) * K_TOT + sslot * 8;
  const unsigned short* ws1 = ws0 + (size_t)128 * K_TOT;
  const int stgoff = wv << 10;  // wave-uniform LDS byte offset within region

#define STAGE_T(t)                                                  \
  do {                                                              \
    const int _bo = (((t) & 3) << 15);                              \
    gload16(xs0 + (size_t)(t) * 32, ldsB + _bo + stgoff);           \
    gload16(xs1 + (size_t)(t) * 32, ldsB + _bo + 8192 + stgoff);    \
    gload16(ws0 + (size_t)(t) * 32, ldsB + _bo + 16384 + stgoff);   \
    gload16(ws1 + (size_t)(t) * 32, ldsB + _bo + 24576 + stgoff);   \
  } while (0)

  // ---- ds_read byte offsets (swizzled: phys_slot = slot ^ ((row>>1)&3)) ----
  const int rl = lane & 15;
  const int q = lane >> 4;
  const int pslot = ((q ^ ((rl >> 1) & 3)) << 4);
  const int aoff = (wr * 128 + rl) * 64 + pslot;           // + mf*1024
  const int boff = 16384 + (wc * 64 + rl) * 64 + pslot;    // + nf*1024

  f32x4 acc[8][4];
#pragma unroll
  for (int i = 0; i < 8; ++i)
#pragma unroll
    for (int j = 0; j < 4; ++j) acc[i][j] = (f32x4){0.f, 0.f, 0.f, 0.f};

  // ---- prologue: stage tiles 0,1,2; wait for tile 0 (4 oldest of 12) ----
  STAGE_T(0); STAGE_T(1); STAGE_T(2);
  asm volatile("s_waitcnt vmcnt(8)" ::: "memory");
  GBARRIER();

#pragma unroll 1
  for (int t = 0; t < NT; ++t) {
    const char* Ab = ldsB + ((t & 3) << 15) + aoff;
    const char* Bb = ldsB + ((t & 3) << 15) + boff;

    // ---- single phase: 12 ds_reads, stage, lgkm0, 32 MFMA, vmcnt, barrier ----
    bf16x8 bfrag[4], afrag[8];
#pragma unroll
    for (int nf = 0; nf < 4; ++nf)
      bfrag[nf] = *reinterpret_cast<const bf16x8*>(Bb + nf * 1024);
#pragma unroll
    for (int mf = 0; mf < 8; ++mf)
      afrag[mf] = *reinterpret_cast<const bf16x8*>(Ab + mf * 1024);
    if (t < NT - 3) STAGE_T(t + 3);

    asm volatile("s_waitcnt lgkmcnt(0)" ::: "memory");
    __builtin_amdgcn_sched_barrier(0);
    __builtin_amdgcn_s_setprio(1);
#pragma unroll
    for (int mf = 0; mf < 8; ++mf)
#pragma unroll
      for (int nf = 0; nf < 4; ++nf)
        acc[mf][nf] = __builtin_amdgcn_mfma_f32_16x16x32_bf16(
            afrag[mf], bfrag[nf], acc[mf][nf], 0, 0, 0);
    __builtin_amdgcn_s_setprio(0);
    __builtin_amdgcn_sched_barrier(0);  // bottom fence: frag lifetimes end here

    // tile boundary: tile t+1 must be resident for ALL waves after barrier
    if (t < NT - 4) {
      asm volatile("s_waitcnt vmcnt(8)" ::: "memory");
    } else if (t == NT - 4) {
      asm volatile("s_waitcnt vmcnt(8)" ::: "memory");
    } else if (t == NT - 3) {
      asm volatile("s_waitcnt vmcnt(4)" ::: "memory");
    } else {
      asm volatile("s_waitcnt vmcnt(0)" ::: "memory");
    }
    GBARRIER();
  }

  // ------------- epilogue (R10/R4 structure): + bias + inter @ B[slot] -------------
  const int slot = idx[m0 >> 11];  // block spans one batch (256 | 2048)
  const float* __restrict__ Bmat = loraB + (size_t)slot * RANK * N_TOT;
  const int gn0 = n0 + wc * 64 + rl;

  float bcv[4][RANK];
  float bv[4];
#pragma unroll
  for (int nf = 0; nf < 4; ++nf) {
    const int gn = gn0 + nf * 16;
    bv[nf] = bias[gn];
#pragma unroll
    for (int p = 0; p < RANK; ++p) bcv[nf][p] = Bmat[(size_t)p * N_TOT + gn];
  }
#pragma unroll
  for (int mf = 0; mf < 8; ++mf) {
    const int gmb = m0 + wr * 128 + mf * 16 + (q << 2);
#pragma unroll
    for (int r = 0; r < 4; ++r) {
      const int gm = gmb + r;
      const float4* ivp = reinterpret_cast<const float4*>(inter + (size_t)gm * RANK);
      const float4 iv0 = ivp[0], iv1 = ivp[1], iv2 = ivp[2], iv3 = ivp[3];
      float* orow = out + (size_t)gm * N_TOT;
#pragma unroll
      for (int nf = 0; nf < 4; ++nf) {
        const float lora =
            iv0.x * bcv[nf][0]  + iv0.y * bcv[nf][1]  + iv0.z * bcv[nf][2]  + iv0.w * bcv[nf][3] +
            iv1.x * bcv[nf][4]  + iv1.y * bcv[nf][5]  + iv1.z * bcv[nf][6]  + iv1.w * bcv[nf][7] +
            iv2.x * bcv[nf][8]  + iv2.y * bcv[nf][9]  + iv2.z * bcv[nf][10] + iv2.w * bcv[nf][11] +
            iv3.x * bcv[nf][12] + iv3.y * bcv[nf][13] + iv3.z * bcv[nf][14] + iv3.w * bcv[nf][15];
        orow[gn0 + nf * 16] = acc[mf][nf][r] + bv[nf] + lora;
      }
    }
  }
#undef STAGE_T
}

// ---------------- host launcher ----------------
extern "C" void kernel_launch(void* const* d_in, const int* in_sizes, int n_in,
                              void* d_out, int out_size, void* d_ws, size_t ws_size,
                              hipStream_t stream) {
  const float* x     = (const float*)d_in[0];  // [8,2048,4096]
  const float* w     = (const float*)d_in[1];  // [4096,4096]
  const float* bias  = (const float*)d_in[2];  // [4096]
  const float* loraA = (const float*)d_in[3];  // [32,4096,16]
  const float* loraB = (const float*)d_in[4];  // [32,16,4096]
  const int*   idx   = (const int*)d_in[5];    // [8]
  float* out = (float*)d_out;

  char* ws = (char*)d_ws;
  unsigned short* xb   = (unsigned short*)ws;                  // 134,217,728 B
  unsigned short* wbuf = (unsigned short*)(ws + 134217728);    //  33,554,432 B
  float* inter = (float*)(ws + 134217728 + 33554432);          //   1,048,576 B

  cvt_bf16_kernel<<<2048, 256, 0, stream>>>(x, xb, M_TOT * K_TOT / 4);
  cvt_bf16_kernel<<<1024, 256, 0, stream>>>(w, wbuf, N_TOT * K_TOT / 4);
  lora_inter_mfma_kernel<<<M_TOT / 64, 256, 0, stream>>>(xb, loraA, idx, inter);
  gemm_fused_kernel<<<(M_TOT / 256) * (N_TOT / 256), 512, 0, stream>>>(
      xb, wbuf, bias, inter, loraB, idx, out);
}

// Round 12
// 663.973 us; speedup vs baseline: 1.4749x; 1.0117x over previous
//
#include <hip/hip_runtime.h>
#include <hip/hip_bf16.h>

// MultiLoRALinear: out = x@W.T + bias + (x @ A[idx]) @ B[idx]
// M=16384, K=4096, N=4096, rank 16.
//
// R12 = R11 + one-tile-deep FRAGMENT pipeline (the m201 mechanism):
//  - R11 measured: tile = 2608 cyc = ds_reads(750, CU) then MFMA(1032) serial
//    + ~800 skew. Fix: read tile t+1's fragments DURING tile t's MFMA groups.
//  - Safe: stage(t+1) is retired once boundary wait is vmcnt(4) (outstanding
//    = stages t+2,t+3), and buf[(t+1)&3] isn't rewritten until stage(t+5).
//  - Ping-pong frag sets fa/fb <-> ga/gb, hand-unrolled x2 (static indices,
//    rule #20). 4 groups of 8 MFMA with 4 ds_reads between, pinned by
//    sched_barrier(0) fences. One lgkmcnt(0) per tile (prev tile's reads).
//  - Liveness: old frags die per-group as new fill; peak ~72 frag regs.
//    Tripwire: WRITE_SIZE > 350MB => spilled => revert.
// Epilogue/pre-pass verbatim R10/R11.

#define M_TOT 16384
#define K_TOT 4096
#define N_TOT 4096
#define RANK 16
#define NT 128   // K_TOT / 32

typedef __attribute__((ext_vector_type(8))) short bf16x8;
typedef __attribute__((ext_vector_type(4))) float f32x4;

// ---------------- fp32 -> bf16 (round-to-nearest-even) ----------------
__device__ __forceinline__ unsigned short f2bf(float f) {
  unsigned int u = __builtin_bit_cast(unsigned int, f);
  u += 0x7fffu + ((u >> 16) & 1u);
  return (unsigned short)(u >> 16);
}

__global__ void cvt_bf16_kernel(const float* __restrict__ src,
                                unsigned short* __restrict__ dst, int n4) {
  int i = blockIdx.x * blockDim.x + threadIdx.x;
  const int stride = gridDim.x * blockDim.x;
  for (; i < n4; i += stride) {
    const float4 v = reinterpret_cast<const float4*>(src)[i];
    ushort4 o;
    o.x = f2bf(v.x); o.y = f2bf(v.y); o.z = f2bf(v.z); o.w = f2bf(v.w);
    reinterpret_cast<ushort4*>(dst)[i] = o;
  }
}

// ------------- inter = x @ A[slot] via MFMA (wave: 16 rows x r16) -------------
__global__ __launch_bounds__(256) void lora_inter_mfma_kernel(
    const unsigned short* __restrict__ xb,
    const float* __restrict__ loraA,
    const int* __restrict__ idx,
    float* __restrict__ inter) {
  const int lane = threadIdx.x & 63;
  const int wv = threadIdx.x >> 6;
  const int m0 = blockIdx.x * 64 + wv * 16;
  const int slot = idx[m0 >> 11];
  const int q = lane >> 4;
  const int c = lane & 15;
  const unsigned short* __restrict__ xrow = xb + (size_t)(m0 + c) * K_TOT + q * 8;
  const float* __restrict__ Abase = loraA + (size_t)slot * K_TOT * RANK + c;

  f32x4 acc = (f32x4){0.f, 0.f, 0.f, 0.f};
#pragma unroll 4
  for (int kt = 0; kt < K_TOT; kt += 32) {
    const bf16x8 af = *reinterpret_cast<const bf16x8*>(xrow + kt);
    const float* __restrict__ Ak = Abase + (size_t)(kt + q * 8) * RANK;
    bf16x8 bfr;
#pragma unroll
    for (int j = 0; j < 8; ++j) bfr[j] = (short)f2bf(Ak[(size_t)j * RANK]);
    acc = __builtin_amdgcn_mfma_f32_16x16x32_bf16(af, bfr, acc, 0, 0, 0);
  }
#pragma unroll
  for (int i = 0; i < 4; ++i)
    inter[(size_t)(m0 + q * 4 + i) * RANK + c] = acc[i];
}

// ---------------- deep-pipelined 256x256 GEMM ----------------
__device__ __forceinline__ void gload16(const void* g, void* l) {
  __builtin_amdgcn_global_load_lds(
      (const __attribute__((address_space(1))) unsigned int*)g,
      (__attribute__((address_space(3))) unsigned int*)l, 16, 0, 0);
}

#define GBARRIER() asm volatile("s_barrier" ::: "memory")
#define RD(p) (*reinterpret_cast<const bf16x8*>(p))

__global__ __launch_bounds__(512, 2) void gemm_fused_kernel(
    const unsigned short* __restrict__ xb,   // [M][K] bf16
    const unsigned short* __restrict__ wb,   // [N][K] bf16
    const float* __restrict__ bias,          // [N]
    const float* __restrict__ inter,         // [M][RANK] f32
    const float* __restrict__ loraB,         // [32][RANK][N] f32
    const int* __restrict__ idx,             // [8]
    float* __restrict__ out) {               // [M][N] f32
  // 4 ring buffers x (A: 256x32 bf16 = 16KB, B: 16KB) = 128 KiB
  __shared__ unsigned short lds[4][16384];
  char* ldsB = (char*)&lds[0][0];

  const int tid = threadIdx.x;
  const int lane = tid & 63;
  const int wv = tid >> 6;   // 0..7
  const int wr = wv >> 2;    // 0..1 (M half)
  const int wc = wv & 3;     // 0..3 (N quarter)

  // XCD-aware bijective swizzle: 1024 wgs, 8 XCDs, 128 per chunk
  const int bid = ((blockIdx.x & 7) << 7) | (blockIdx.x >> 3);
  const int m0 = (bid >> 4) << 8;   // 64 M-panels
  const int n0 = (bid & 15) << 8;   // 16 N-panels

  // ---- staging source (pre-permuted by the LDS swizzle involution) ----
  const int srow = tid >> 2;                        // 0..127
  const int sslot = (tid & 3) ^ ((srow >> 1) & 3);  // 16B slot within 64B row
  const unsigned short* xs0 = xb + (size_t)(m0 + srow) * K_TOT + sslot * 8;
  const unsigned short* xs1 = xs0 + (size_t)128 * K_TOT;
  const unsigned short* ws0 = wb + (size_t)(n0 + srow) * K_TOT + sslot * 8;
  const unsigned short* ws1 = ws0 + (size_t)128 * K_TOT;
  const int stgoff = wv << 10;  // wave-uniform LDS byte offset within region

#define STAGE_T(t)                                                  \
  do {                                                              \
    const int _bo = (((t) & 3) << 15);                              \
    gload16(xs0 + (size_t)(t) * 32, ldsB + _bo + stgoff);           \
    gload16(xs1 + (size_t)(t) * 32, ldsB + _bo + 8192 + stgoff);    \
    gload16(ws0 + (size_t)(t) * 32, ldsB + _bo + 16384 + stgoff);   \
    gload16(ws1 + (size_t)(t) * 32, ldsB + _bo + 24576 + stgoff);   \
  } while (0)

  // ---- ds_read byte offsets (swizzled: phys_slot = slot ^ ((row>>1)&3)) ----
  const int rl = lane & 15;
  const int q = lane >> 4;
  const int pslot = ((q ^ ((rl >> 1) & 3)) << 4);
  const int aoff = (wr * 128 + rl) * 64 + pslot;           // + mf*1024
  const int boff = 16384 + (wc * 64 + rl) * 64 + pslot;    // + nf*1024

  f32x4 acc[8][4];
#pragma unroll
  for (int i = 0; i < 8; ++i)
#pragma unroll
    for (int j = 0; j < 4; ++j) acc[i][j] = (f32x4){0.f, 0.f, 0.f, 0.f};

  // frag ping-pong sets
  bf16x8 fa[8], fb[4], ga[8], gb[4];
#pragma unroll
  for (int i = 0; i < 8; ++i) ga[i] = (bf16x8){0,0,0,0,0,0,0,0};
#pragma unroll
  for (int i = 0; i < 4; ++i) gb[i] = (bf16x8){0,0,0,0,0,0,0,0};

  // ---- prologue: stage 0,1,2; retire 0 and 1; preload frags(0) ----
  STAGE_T(0); STAGE_T(1); STAGE_T(2);
  asm volatile("s_waitcnt vmcnt(4)" ::: "memory");
  GBARRIER();
  {
    const char* Ab0 = ldsB + aoff;
    const char* Bb0 = ldsB + boff;
#pragma unroll
    for (int i = 0; i < 8; ++i) fa[i] = RD(Ab0 + i * 1024);
#pragma unroll
    for (int i = 0; i < 4; ++i) fb[i] = RD(Bb0 + i * 1024);
  }

  // one MFMA group: acc[2g..2g+1][0..3]
#define MG(CA, CB, g)                                                     \
  do {                                                                    \
    _Pragma("unroll")                                                     \
    for (int nf = 0; nf < 4; ++nf)                                        \
      acc[2 * (g)][nf] = __builtin_amdgcn_mfma_f32_16x16x32_bf16(         \
          CA[2 * (g)], CB[nf], acc[2 * (g)][nf], 0, 0, 0);                \
    _Pragma("unroll")                                                     \
    for (int nf = 0; nf < 4; ++nf)                                        \
      acc[2 * (g) + 1][nf] = __builtin_amdgcn_mfma_f32_16x16x32_bf16(     \
          CA[2 * (g) + 1], CB[nf], acc[2 * (g) + 1][nf], 0, 0, 0);        \
  } while (0)

#define TILE_BODY(CA, CB, NA, NB, T)                                      \
  do {                                                                    \
    const int _t = (T);                                                   \
    const char* Abn = ldsB + (((_t + 1) & 3) << 15) + aoff;               \
    const char* Bbn = ldsB + (((_t + 1) & 3) << 15) + boff;               \
    const bool rd = _t < NT - 1;                                          \
    asm volatile("s_waitcnt lgkmcnt(0)" ::: "memory");                    \
    __builtin_amdgcn_sched_barrier(0);                                    \
    __builtin_amdgcn_s_setprio(1);                                        \
    MG(CA, CB, 0);                                                        \
    __builtin_amdgcn_s_setprio(0);                                        \
    __builtin_amdgcn_sched_barrier(0);                                    \
    if (rd) {                                                             \
      NA[0] = RD(Abn);          NA[1] = RD(Abn + 1024);                   \
      NA[2] = RD(Abn + 2048);   NA[3] = RD(Abn + 3072);                   \
    }                                                                     \
    __builtin_amdgcn_sched_barrier(0);                                    \
    __builtin_amdgcn_s_setprio(1);                                        \
    MG(CA, CB, 1);                                                        \
    __builtin_amdgcn_s_setprio(0);                                        \
    __builtin_amdgcn_sched_barrier(0);                                    \
    if (rd) {                                                             \
      NA[4] = RD(Abn + 4096);   NA[5] = RD(Abn + 5120);                   \
      NA[6] = RD(Abn + 6144);   NA[7] = RD(Abn + 7168);                   \
    }                                                                     \
    __builtin_amdgcn_sched_barrier(0);                                    \
    __builtin_amdgcn_s_setprio(1);                                        \
    MG(CA, CB, 2);                                                        \
    __builtin_amdgcn_s_setprio(0);                                        \
    __builtin_amdgcn_sched_barrier(0);                                    \
    if (rd) {                                                             \
      NB[0] = RD(Bbn);          NB[1] = RD(Bbn + 1024);                   \
      NB[2] = RD(Bbn + 2048);   NB[3] = RD(Bbn + 3072);                   \
    }                                                                     \
    if (_t < NT - 3) STAGE_T(_t + 3);                                     \
    __builtin_amdgcn_sched_barrier(0);                                    \
    __builtin_amdgcn_s_setprio(1);                                        \
    MG(CA, CB, 3);                                                        \
    __builtin_amdgcn_s_setprio(0);                                        \
    __builtin_amdgcn_sched_barrier(0);                                    \
    if (_t <= NT - 4) {                                                   \
      asm volatile("s_waitcnt vmcnt(4)" ::: "memory");                    \
    } else {                                                              \
      asm volatile("s_waitcnt vmcnt(0)" ::: "memory");                    \
    }                                                                     \
    GBARRIER();                                                           \
  } while (0)

#pragma unroll 1
  for (int tp = 0; tp < NT; tp += 2) {
    TILE_BODY(fa, fb, ga, gb, tp);
    TILE_BODY(ga, gb, fa, fb, tp + 1);
  }

  // ------------- epilogue (R10/R4 structure): + bias + inter @ B[slot] -------------
  const int slot = idx[m0 >> 11];  // block spans one batch (256 | 2048)
  const float* __restrict__ Bmat = loraB + (size_t)slot * RANK * N_TOT;
  const int gn0 = n0 + wc * 64 + rl;

  float bcv[4][RANK];
  float bv[4];
#pragma unroll
  for (int nf = 0; nf < 4; ++nf) {
    const int gn = gn0 + nf * 16;
    bv[nf] = bias[gn];
#pragma unroll
    for (int p = 0; p < RANK; ++p) bcv[nf][p] = Bmat[(size_t)p * N_TOT + gn];
  }
#pragma unroll
  for (int mf = 0; mf < 8; ++mf) {
    const int gmb = m0 + wr * 128 + mf * 16 + (q << 2);
#pragma unroll
    for (int r = 0; r < 4; ++r) {
      const int gm = gmb + r;
      const float4* ivp = reinterpret_cast<const float4*>(inter + (size_t)gm * RANK);
      const float4 iv0 = ivp[0], iv1 = ivp[1], iv2 = ivp[2], iv3 = ivp[3];
      float* orow = out + (size_t)gm * N_TOT;
#pragma unroll
      for (int nf = 0; nf < 4; ++nf) {
        const float lora =
            iv0.x * bcv[nf][0]  + iv0.y * bcv[nf][1]  + iv0.z * bcv[nf][2]  + iv0.w * bcv[nf][3] +
            iv1.x * bcv[nf][4]  + iv1.y * bcv[nf][5]  + iv1.z * bcv[nf][6]  + iv1.w * bcv[nf][7] +
            iv2.x * bcv[nf][8]  + iv2.y * bcv[nf][9]  + iv2.z * bcv[nf][10] + iv2.w * bcv[nf][11] +
            iv3.x * bcv[nf][12] + iv3.y * bcv[nf][13] + iv3.z * bcv[nf][14] + iv3.w * bcv[nf][15];
        orow[gn0 + nf * 16] = acc[mf][nf][r] + bv[nf] + lora;
      }
    }
  }
#undef STAGE_T
#undef TILE_BODY
#undef MG
}

// ---------------- host launcher ----------------
extern "C" void kernel_launch(void* const* d_in, const int* in_sizes, int n_in,
                              void* d_out, int out_size, void* d_ws, size_t ws_size,
                              hipStream_t stream) {
  const float* x     = (const float*)d_in[0];  // [8,2048,4096]
  const float* w     = (const float*)d_in[1];  // [4096,4096]
  const float* bias  = (const float*)d_in[2];  // [4096]
  const float* loraA = (const float*)d_in[3];  // [32,4096,16]
  const float* loraB = (const float*)d_in[4];  // [32,16,4096]
  const int*   idx   = (const int*)d_in[5];    // [8]
  float* out = (float*)d_out;

  char* ws = (char*)d_ws;
  unsigned short* xb   = (unsigned short*)ws;                  // 134,217,728 B
  unsigned short* wbuf = (unsigned short*)(ws + 134217728);    //  33,554,432 B
  float* inter = (float*)(ws + 134217728 + 33554432);          //   1,048,576 B

  cvt_bf16_kernel<<<2048, 256, 0, stream>>>(x, xb, M_TOT * K_TOT / 4);
  cvt_bf16_kernel<<<1024, 256, 0, stream>>>(w, wbuf, N_TOT * K_TOT / 4);
  lora_inter_mfma_kernel<<<M_TOT / 64, 256, 0, stream>>>(xb, loraA, idx, inter);
  gemm_fused_kernel<<<(M_TOT / 256) * (N_TOT / 256), 512, 0, stream>>>(
      xb, wbuf, bias, inter, loraB, idx, out);
}